// Round 1
// baseline (132.843 us; speedup 1.0000x reference)
//
#include <hip/hip_runtime.h>
#include <math.h>

// Problem constants (from reference): N=32768 points, D=16, F=4096 features, M=16
#define NPTS  32768
#define DIMD  16
#define NFEAT 4096
#define MDIM  16

constexpr int WAVES          = 8;              // waves per block
constexpr int BLOCK          = WAVES * 64;     // 512 threads
constexpr int ROWS_PER_BLOCK = 64;             // one row per lane
constexpr int F_PER_WAVE     = NFEAT / WAVES;  // 512 features per wave

// out[n,m] = sqrt(2/F) * sum_f cos(x[n,:]·a[f,:] + b[f]) * W[f*M+m]
__global__ __launch_bounds__(BLOCK) void km_fused(
    const float* __restrict__ x, const float* __restrict__ a,
    const float* __restrict__ b, const float* __restrict__ W,
    float* __restrict__ out)
{
    const int lane = threadIdx.x & 63;
    const int wave = threadIdx.x >> 6;
    const int row  = blockIdx.x * ROWS_PER_BLOCK + lane;

    // Load this lane's x row (16 floats, coalesced float4s), keep in VGPRs.
    float xr[DIMD];
    {
        const float4* xp = reinterpret_cast<const float4*>(x + (size_t)row * DIMD);
        #pragma unroll
        for (int i = 0; i < 4; ++i) {
            float4 v = xp[i];
            xr[4 * i + 0] = v.x; xr[4 * i + 1] = v.y;
            xr[4 * i + 2] = v.z; xr[4 * i + 3] = v.w;
        }
    }

    float acc[MDIM];
    #pragma unroll
    for (int m = 0; m < MDIM; ++m) acc[m] = 0.f;

    // Wave-uniform feature chunk. readfirstlane anchors the base in an SGPR so
    // a/b/W loads compile to scalar (s_load) broadcasts, not per-lane VMEM.
    const int fbase = __builtin_amdgcn_readfirstlane(wave * F_PER_WAVE);
    const float* __restrict__ ab = a + (size_t)fbase * DIMD;
    const float* __restrict__ wb = W + (size_t)fbase * MDIM;
    const float* __restrict__ bb = b + fbase;

    constexpr float INV2PI = 0.15915494309189535f;  // v_cos_f32 takes revolutions

    #pragma unroll 2
    for (int fi = 0; fi < F_PER_WAVE; ++fi) {
        const float* ar = ab + fi * DIMD;
        const float* wr = wb + fi * MDIM;
        // 4-way split dot product: 4 independent FMA chains of depth 4.
        float d0 = 0.f, d1 = 0.f, d2 = 0.f, d3 = 0.f;
        #pragma unroll
        for (int d = 0; d < 4; ++d) {
            d0 = fmaf(xr[d],      ar[d],      d0);
            d1 = fmaf(xr[4 + d],  ar[4 + d],  d1);
            d2 = fmaf(xr[8 + d],  ar[8 + d],  d2);
            d3 = fmaf(xr[12 + d], ar[12 + d], d3);
        }
        float t = ((d0 + d1) + (d2 + d3)) + bb[fi];
        float c = __builtin_amdgcn_cosf(t * INV2PI);  // |t|*INV2PI <= ~6 rev, in HW range
        #pragma unroll
        for (int m = 0; m < MDIM; ++m)
            acc[m] = fmaf(c, wr[m], acc[m]);
    }

    // Cross-wave reduction: each row's 16 outputs summed over 8 waves via LDS.
    __shared__ float red[WAVES][ROWS_PER_BLOCK][MDIM];  // 32 KiB
    #pragma unroll
    for (int m = 0; m < MDIM; m += 4) {
        *reinterpret_cast<float4*>(&red[wave][lane][m]) =
            make_float4(acc[m], acc[m + 1], acc[m + 2], acc[m + 3]);
    }
    __syncthreads();

    constexpr float SCALE = 0.02209708691207961f;  // sqrt(2/4096)
    for (int o = threadIdx.x; o < ROWS_PER_BLOCK * MDIM; o += BLOCK) {
        const int r = o >> 4, m = o & 15;
        float s = 0.f;
        #pragma unroll
        for (int w = 0; w < WAVES; ++w) s += red[w][r][m];
        out[((size_t)blockIdx.x * ROWS_PER_BLOCK + r) * MDIM + m] = s * SCALE;
    }
}

extern "C" void kernel_launch(void* const* d_in, const int* in_sizes, int n_in,
                              void* d_out, int out_size, void* d_ws, size_t ws_size,
                              hipStream_t stream) {
    const float* x = (const float*)d_in[0];  // [N, D]
    const float* a = (const float*)d_in[1];  // [F, D]
    const float* b = (const float*)d_in[2];  // [F]
    const float* W = (const float*)d_in[3];  // [F*M]
    float* out = (float*)d_out;              // [N, M] fp32

    dim3 grid(NPTS / ROWS_PER_BLOCK);        // 512 blocks
    km_fused<<<grid, dim3(BLOCK), 0, stream>>>(x, a, b, W, out);
}

// Round 2
// 37.843 us; speedup vs baseline: 3.5103x; 3.5103x over previous
//
#include <hip/hip_runtime.h>
#include <hip/hip_bf16.h>
#include <math.h>

// Problem constants: N=32768 points, D=16, F=4096 features, M=16
#define NPTS  32768
#define DIMD  16
#define NFEAT 4096
#define MDIM  16

typedef short bf16x8 __attribute__((ext_vector_type(8)));
typedef float f32x16 __attribute__((ext_vector_type(16)));
typedef float f32x4v __attribute__((ext_vector_type(4)));

constexpr float SCALE  = 0.02209708691207961f;   // sqrt(2/4096), folded into W at prep
constexpr float INV2PI = 0.15915494309189535f;   // v_cos_f32 takes revolutions

// ---- d_ws scratch layout ----
// A1 (a-chunk bf16 A-frags):  [128 steps][64 lanes][8 bf16]      @ 0       (128 KiB)
// A2 (W' bf16 A-frags):       [128 steps][2 tiles][64][8 bf16]   @ 128 KiB (256 KiB)
#define WS_A1_OFF 0
#define WS_A2_OFF (128 * 64 * 8 * 2)                  // bytes
#define WS_NEEDED (WS_A2_OFF + 128 * 2 * 64 * 8 * 2)  // 384 KiB

__device__ __forceinline__ unsigned short f2bf(float x) {  // RNE f32->bf16
    unsigned int u = __float_as_uint(x);
    u += 0x7fff + ((u >> 16) & 1);
    return (unsigned short)(u >> 16);
}
__device__ __forceinline__ unsigned int cvtpk(float lo, float hi) {
    unsigned int r;
    asm("v_cvt_pk_bf16_f32 %0, %1, %2" : "=v"(r) : "v"(lo), "v"(hi));
    return r;
}
// a' = [a_lo | b_lo], b' = [a_hi | b_hi]
__device__ __forceinline__ void swap32(unsigned int& a, unsigned int& b) {
    asm("v_permlane32_swap_b32 %0, %1" : "+v"(a), "+v"(b));
}

// Pack a -> bf16 GEMM1 A-frags, W -> scaled bf16 GEMM2 A-frags.
// MFMA 32x32x16 A-layout: lane l holds row (l&31), k = (l>>5)*8 + j, j=0..7.
__global__ __launch_bounds__(64) void km_prep(
    const float* __restrict__ a, const float* __restrict__ W,
    unsigned short* __restrict__ ws_a1, unsigned short* __restrict__ ws_a2)
{
    const int s  = blockIdx.x;    // K-step 0..127 (32 features each)
    const int l  = threadIdx.x;   // 0..63
    const int h  = l >> 5;
    const int nl = l & 31;

    // A1: rows = features F0+(l&31), k = dims 8h..8h+7
    {
        const int f = 32 * s + nl;
        const float* ap = a + f * DIMD + 8 * h;
        union { unsigned short u[8]; bf16x8 v; } cv;
        #pragma unroll
        for (int j = 0; j < 8; ++j) cv.u[j] = f2bf(ap[j]);
        *reinterpret_cast<bf16x8*>(ws_a1 + ((size_t)s * 64 + l) * 8) = cv.v;
    }
    // A2: rows = output col m (l&31, valid m<16 else zero), k = features 16q+8h+j
    #pragma unroll
    for (int q = 0; q < 2; ++q) {
        union { unsigned short u[8]; bf16x8 v; } cv;
        #pragma unroll
        for (int j = 0; j < 8; ++j) {
            float v = 0.f;
            if (nl < MDIM) {
                const int f = 32 * s + 16 * q + 8 * h + j;
                v = W[(size_t)f * MDIM + nl] * SCALE;
            }
            cv.u[j] = f2bf(v);
        }
        *reinterpret_cast<bf16x8*>(ws_a2 + (((size_t)s * 2 + q) * 64 + l) * 8) = cv.v;
    }
}

// Main: 1024 blocks x 512 thr. Block owns 32 output rows; wave w owns feature
// chunk w (512 features = 16 K-steps). No LDS/barriers in the K-loop.
__global__ __launch_bounds__(512, 4) void km_mfma(
    const float* __restrict__ x, const float* __restrict__ b,
    const unsigned short* __restrict__ ws_a1, const unsigned short* __restrict__ ws_a2,
    float* __restrict__ out)
{
    const int tid = threadIdx.x;
    const int l   = tid & 63;
    const int w   = tid >> 6;          // wave = feature chunk 0..7
    const int h   = l >> 5;
    const int nl  = l & 31;
    const int rowbase = blockIdx.x * 32;

    // GEMM1 B-frag: x^T[16d x 32n]; lane: col n = rowbase+nl, k = d = 8h+j. Load once.
    bf16x8 xf;
    {
        const float* xp = x + (size_t)(rowbase + nl) * DIMD + 8 * h;
        union { unsigned short u[8]; bf16x8 v; } cv;
        #pragma unroll
        for (int j = 0; j < 8; ++j) cv.u[j] = f2bf(xp[j]);
        xf = cv.v;
    }

    f32x16 acc;
    #pragma unroll
    for (int i = 0; i < 16; ++i) acc[i] = 0.f;

    const bool valid = (nl < MDIM);

    #pragma unroll 2
    for (int s = 0; s < 16; ++s) {
        const int sg = w * 16 + s;
        const int F0 = 32 * sg;

        // frag loads (L2-resident scratch, per-lane 16B coalesced)
        bf16x8 a1 = *reinterpret_cast<const bf16x8*>(ws_a1 + ((size_t)sg * 64 + l) * 8);
        bf16x8 a2t0 = {}, a2t1 = {};
        if (valid) {
            a2t0 = *reinterpret_cast<const bf16x8*>(ws_a2 + (((size_t)sg * 2 + 0) * 64 + l) * 8);
            a2t1 = *reinterpret_cast<const bf16x8*>(ws_a2 + (((size_t)sg * 2 + 1) * 64 + l) * 8);
        }
        // bias as GEMM1 C-in: c[reg r] = b[F0 + (r&3) + 8*(r>>2) + 4h]
        f32x16 c;
        #pragma unroll
        for (int g = 0; g < 4; ++g) {
            f32x4v bb = *reinterpret_cast<const f32x4v*>(b + F0 + 8 * g + 4 * h);
            c[4 * g + 0] = bb[0]; c[4 * g + 1] = bb[1];
            c[4 * g + 2] = bb[2]; c[4 * g + 3] = bb[3];
        }

        // GEMM1: S[f, n] = a·x^T + b   (S reg r -> f = F0 + (r&3)+8(r>>2)+4h, col n = nl)
        f32x16 S = __builtin_amdgcn_mfma_f32_32x32x16_bf16(a1, xf, c, 0, 0, 0);

        // phi = cos(S), pack to bf16 pairs; dw[i] = pk(phi[2i], phi[2i+1])
        unsigned int dw[8];
        #pragma unroll
        for (int i = 0; i < 8; ++i) {
            float p0 = __builtin_amdgcn_cosf(S[2 * i]     * INV2PI);
            float p1 = __builtin_amdgcn_cosf(S[2 * i + 1] * INV2PI);
            dw[i] = cvtpk(p0, p1);
        }
        // Build GEMM2 B-frags phi[16f x 32n] via half-swaps:
        // tile0 (features F0..F0+15) from regs 0-7, tile1 (F0+16..F0+31) from regs 8-15.
        swap32(dw[0], dw[2]); swap32(dw[1], dw[3]);
        swap32(dw[4], dw[6]); swap32(dw[5], dw[7]);
        union { unsigned int u[4]; bf16x8 v; } p0, p1;
        p0.u[0] = dw[0]; p0.u[1] = dw[1]; p0.u[2] = dw[2]; p0.u[3] = dw[3];
        p1.u[0] = dw[4]; p1.u[1] = dw[5]; p1.u[2] = dw[6]; p1.u[3] = dw[7];

        // GEMM2: out^T[m, n] += W'[32m x 16f] · phi[16f x 32n]
        acc = __builtin_amdgcn_mfma_f32_32x32x16_bf16(a2t0, p0.v, acc, 0, 0, 0);
        acc = __builtin_amdgcn_mfma_f32_32x32x16_bf16(a2t1, p1.v, acc, 0, 0, 0);
    }

    // acc regs 0..7 hold m = (r&3)+8*(r>>2)+4h for col n = nl (regs 8-15 are the m>=16 pad).
    __shared__ float red[8][64][8];   // 16 KiB
    #pragma unroll
    for (int r = 0; r < 8; ++r) red[w][l][r] = acc[r];
    __syncthreads();

    // thread t -> output (n_local = t>>4, m = t&15); source lane/reg is unique:
    const int n_l = tid >> 4;
    const int m   = tid & 15;
    const int li  = n_l + 32 * ((m >> 2) & 1);
    const int r   = (m & 3) + 4 * (m >> 3);
    float ssum = 0.f;
    #pragma unroll
    for (int ww = 0; ww < 8; ++ww) ssum += red[ww][li][r];
    out[(size_t)(rowbase + n_l) * MDIM + m] = ssum;
}

// ---------------- fallback (round-1 kernel, known-correct) ----------------
constexpr int FB_WAVES = 8, FB_BLOCK = 512, FB_ROWS = 64, FB_FPW = NFEAT / FB_WAVES;
__global__ __launch_bounds__(FB_BLOCK) void km_fused(
    const float* __restrict__ x, const float* __restrict__ a,
    const float* __restrict__ b, const float* __restrict__ W,
    float* __restrict__ out)
{
    const int lane = threadIdx.x & 63, wave = threadIdx.x >> 6;
    const int row  = blockIdx.x * FB_ROWS + lane;
    float xr[DIMD];
    const float4* xp = reinterpret_cast<const float4*>(x + (size_t)row * DIMD);
    #pragma unroll
    for (int i = 0; i < 4; ++i) {
        float4 v = xp[i];
        xr[4*i] = v.x; xr[4*i+1] = v.y; xr[4*i+2] = v.z; xr[4*i+3] = v.w;
    }
    float acc[MDIM];
    #pragma unroll
    for (int m = 0; m < MDIM; ++m) acc[m] = 0.f;
    const int fbase = __builtin_amdgcn_readfirstlane(wave * FB_FPW);
    const float* ab = a + (size_t)fbase * DIMD;
    const float* wb = W + (size_t)fbase * MDIM;
    const float* bb = b + fbase;
    #pragma unroll 2
    for (int fi = 0; fi < FB_FPW; ++fi) {
        const float* ar = ab + fi * DIMD;
        const float* wr = wb + fi * MDIM;
        float d0 = 0.f, d1 = 0.f, d2 = 0.f, d3 = 0.f;
        #pragma unroll
        for (int d = 0; d < 4; ++d) {
            d0 = fmaf(xr[d], ar[d], d0);       d1 = fmaf(xr[4+d], ar[4+d], d1);
            d2 = fmaf(xr[8+d], ar[8+d], d2);   d3 = fmaf(xr[12+d], ar[12+d], d3);
        }
        float t = ((d0 + d1) + (d2 + d3)) + bb[fi];
        float cc = __builtin_amdgcn_cosf(t * INV2PI);
        #pragma unroll
        for (int m = 0; m < MDIM; ++m) acc[m] = fmaf(cc, wr[m], acc[m]);
    }
    __shared__ float red[FB_WAVES][FB_ROWS][MDIM];
    #pragma unroll
    for (int m = 0; m < MDIM; m += 4)
        *reinterpret_cast<float4*>(&red[wave][lane][m]) =
            make_float4(acc[m], acc[m+1], acc[m+2], acc[m+3]);
    __syncthreads();
    for (int o = threadIdx.x; o < FB_ROWS * MDIM; o += FB_BLOCK) {
        const int rr = o >> 4, m = o & 15;
        float s = 0.f;
        #pragma unroll
        for (int ww = 0; ww < FB_WAVES; ++ww) s += red[ww][rr][m];
        out[((size_t)blockIdx.x * FB_ROWS + rr) * MDIM + m] = s * SCALE;
    }
}

extern "C" void kernel_launch(void* const* d_in, const int* in_sizes, int n_in,
                              void* d_out, int out_size, void* d_ws, size_t ws_size,
                              hipStream_t stream) {
    const float* x = (const float*)d_in[0];  // [N, D]
    const float* a = (const float*)d_in[1];  // [F, D]
    const float* b = (const float*)d_in[2];  // [F]
    const float* W = (const float*)d_in[3];  // [F*M]
    float* out = (float*)d_out;              // [N, M]

    if (ws_size >= (size_t)WS_NEEDED) {
        unsigned short* ws_a1 = (unsigned short*)((char*)d_ws + WS_A1_OFF);
        unsigned short* ws_a2 = (unsigned short*)((char*)d_ws + WS_A2_OFF);
        km_prep<<<dim3(128), dim3(64), 0, stream>>>(a, W, ws_a1, ws_a2);
        km_mfma<<<dim3(NPTS / 32), dim3(512), 0, stream>>>(x, b, ws_a1, ws_a2, out);
    } else {
        km_fused<<<dim3(NPTS / FB_ROWS), dim3(FB_BLOCK), 0, stream>>>(x, a, b, W, out);
    }
}

// Round 3
// 29.131 us; speedup vs baseline: 4.5602x; 1.2991x over previous
//
#include <hip/hip_runtime.h>
#include <hip/hip_bf16.h>
#include <math.h>

// Problem constants: N=32768 points, D=16, F=4096 features, M=16
#define NPTS  32768
#define DIMD  16
#define NFEAT 4096
#define MDIM  16

typedef short bf16x8 __attribute__((ext_vector_type(8)));
typedef float f32x16 __attribute__((ext_vector_type(16)));
typedef float f32x4v __attribute__((ext_vector_type(4)));

constexpr float SCALE  = 0.02209708691207961f;   // sqrt(2/4096), folded into W at prep
constexpr float INV2PI = 0.15915494309189535f;   // folded into a,b at prep (cos in revs)

// ---- d_ws scratch layout ----
// A1 (a*INV2PI bf16 A-frags): [128 steps][64 lanes][8 bf16]    @ 0       (128 KiB)
// A2 (W*SCALE bf16 A-frags):  [128 steps][2 tiles][64][8 bf16] @ 128 KiB (256 KiB)
// BS (b*INV2PI fp32):         [4096]                           @ 384 KiB ( 16 KiB)
#define WS_A1_OFF 0
#define WS_A2_OFF 131072
#define WS_BS_OFF 393216
#define WS_NEEDED 409600

__device__ __forceinline__ unsigned short f2bf(float x) {  // RNE f32->bf16
    unsigned int u = __float_as_uint(x);
    u += 0x7fff + ((u >> 16) & 1);
    return (unsigned short)(u >> 16);
}
__device__ __forceinline__ unsigned int cvtpk(float lo, float hi) {
    unsigned int r;
    asm("v_cvt_pk_bf16_f32 %0, %1, %2" : "=v"(r) : "v"(lo), "v"(hi));
    return r;
}
// a' = [a_lo | b_lo], b' = [a_hi | b_hi]
__device__ __forceinline__ void swap32(unsigned int& a, unsigned int& b) {
    asm("v_permlane32_swap_b32 %0, %1" : "+v"(a), "+v"(b));
}

// Pack a*INV2PI -> bf16 GEMM1 A-frags, W*SCALE -> bf16 GEMM2 A-frags, b*INV2PI fp32.
// MFMA 32x32x16 A-layout: lane l holds row (l&31), k = (l>>5)*8 + j.
__global__ __launch_bounds__(64) void km_prep(
    const float* __restrict__ a, const float* __restrict__ b, const float* __restrict__ W,
    unsigned short* __restrict__ ws_a1, unsigned short* __restrict__ ws_a2,
    float* __restrict__ ws_bs)
{
    const int s  = blockIdx.x;    // K-step 0..127 (32 features each)
    const int l  = threadIdx.x;
    const int h  = l >> 5;
    const int nl = l & 31;

    {   // A1: rows = features 32s+(l&31), k = dims 8h..8h+7, pre-scaled by 1/2pi
        const int f = 32 * s + nl;
        const float* ap = a + f * DIMD + 8 * h;
        union { unsigned short u[8]; bf16x8 v; } cv;
        #pragma unroll
        for (int j = 0; j < 8; ++j) cv.u[j] = f2bf(ap[j] * INV2PI);
        *reinterpret_cast<bf16x8*>(ws_a1 + ((size_t)s * 64 + l) * 8) = cv.v;
    }
    #pragma unroll
    for (int q = 0; q < 2; ++q) {  // A2: rows = m (pad m>=16 with 0), k = features
        union { unsigned short u[8]; bf16x8 v; } cv;
        #pragma unroll
        for (int j = 0; j < 8; ++j) {
            float v = 0.f;
            if (nl < MDIM) {
                const int f = 32 * s + 16 * q + 8 * h + j;
                v = W[(size_t)f * MDIM + nl] * SCALE;
            }
            cv.u[j] = f2bf(v);
        }
        *reinterpret_cast<bf16x8*>(ws_a2 + (((size_t)s * 2 + q) * 64 + l) * 8) = cv.v;
    }
    if (l < 32) ws_bs[32 * s + l] = b[32 * s + l] * INV2PI;
}

// Main: 512 blocks x 512 thr. Block owns 64 output rows (2 n-tiles of 32);
// wave w owns feature chunk w (512 features = 16 K-steps). Frag/bias loads are
// shared across both tiles -> half the L2 traffic of 1-tile blocking.
__global__ __launch_bounds__(512, 4) void km_mfma(
    const float* __restrict__ x,
    const unsigned short* __restrict__ ws_a1, const unsigned short* __restrict__ ws_a2,
    const float* __restrict__ ws_bs, float* __restrict__ out)
{
    const int tid = threadIdx.x;
    const int l   = tid & 63;
    const int w   = tid >> 6;          // wave = feature chunk 0..7
    const int h   = l >> 5;
    const int nl  = l & 31;
    const int rowbase = blockIdx.x * 64;

    // GEMM1 B-frags: x^T[16d x 32n] per tile; lane: col n, k = d = 8h+j.
    bf16x8 xf0, xf1;
    {
        const float* xp0 = x + (size_t)(rowbase + nl) * DIMD + 8 * h;
        const float* xp1 = x + (size_t)(rowbase + 32 + nl) * DIMD + 8 * h;
        union { unsigned short u[8]; bf16x8 v; } c0, c1;
        #pragma unroll
        for (int j = 0; j < 8; ++j) { c0.u[j] = f2bf(xp0[j]); c1.u[j] = f2bf(xp1[j]); }
        xf0 = c0.v; xf1 = c1.v;
    }

    f32x16 acc0, acc1;
    #pragma unroll
    for (int i = 0; i < 16; ++i) { acc0[i] = 0.f; acc1[i] = 0.f; }

    const bool valid = (nl < MDIM);

    #pragma unroll 2
    for (int s = 0; s < 16; ++s) {
        const int sg = w * 16 + s;
        const int F0 = 32 * sg;

        bf16x8 a1 = *reinterpret_cast<const bf16x8*>(ws_a1 + ((size_t)sg * 64 + l) * 8);
        bf16x8 a2t0 = {}, a2t1 = {};
        if (valid) {
            a2t0 = *reinterpret_cast<const bf16x8*>(ws_a2 + (((size_t)sg * 2 + 0) * 64 + l) * 8);
            a2t1 = *reinterpret_cast<const bf16x8*>(ws_a2 + (((size_t)sg * 2 + 1) * 64 + l) * 8);
        }

        // ---- tile 0 ----
        {
            f32x16 c;   // bias C-in: c[r] = bs[F0 + (r&3) + 8*(r>>2) + 4h], prescaled
            #pragma unroll
            for (int g = 0; g < 4; ++g) {
                f32x4v bb = *reinterpret_cast<const f32x4v*>(ws_bs + F0 + 8 * g + 4 * h);
                c[4*g] = bb[0]; c[4*g+1] = bb[1]; c[4*g+2] = bb[2]; c[4*g+3] = bb[3];
            }
            f32x16 S = __builtin_amdgcn_mfma_f32_32x32x16_bf16(a1, xf0, c, 0, 0, 0);
            unsigned int dw[8];
            #pragma unroll
            for (int i = 0; i < 8; ++i)
                dw[i] = cvtpk(__builtin_amdgcn_cosf(S[2*i]), __builtin_amdgcn_cosf(S[2*i+1]));
            swap32(dw[0], dw[2]); swap32(dw[1], dw[3]);
            swap32(dw[4], dw[6]); swap32(dw[5], dw[7]);
            union { unsigned int u[4]; bf16x8 v; } p0, p1;
            p0.u[0]=dw[0]; p0.u[1]=dw[1]; p0.u[2]=dw[2]; p0.u[3]=dw[3];
            p1.u[0]=dw[4]; p1.u[1]=dw[5]; p1.u[2]=dw[6]; p1.u[3]=dw[7];
            acc0 = __builtin_amdgcn_mfma_f32_32x32x16_bf16(a2t0, p0.v, acc0, 0, 0, 0);
            acc0 = __builtin_amdgcn_mfma_f32_32x32x16_bf16(a2t1, p1.v, acc0, 0, 0, 0);
        }
        // ---- tile 1 (bias reload is an L1 hit) ----
        {
            f32x16 c;
            #pragma unroll
            for (int g = 0; g < 4; ++g) {
                f32x4v bb = *reinterpret_cast<const f32x4v*>(ws_bs + F0 + 8 * g + 4 * h);
                c[4*g] = bb[0]; c[4*g+1] = bb[1]; c[4*g+2] = bb[2]; c[4*g+3] = bb[3];
            }
            f32x16 S = __builtin_amdgcn_mfma_f32_32x32x16_bf16(a1, xf1, c, 0, 0, 0);
            unsigned int dw[8];
            #pragma unroll
            for (int i = 0; i < 8; ++i)
                dw[i] = cvtpk(__builtin_amdgcn_cosf(S[2*i]), __builtin_amdgcn_cosf(S[2*i+1]));
            swap32(dw[0], dw[2]); swap32(dw[1], dw[3]);
            swap32(dw[4], dw[6]); swap32(dw[5], dw[7]);
            union { unsigned int u[4]; bf16x8 v; } p0, p1;
            p0.u[0]=dw[0]; p0.u[1]=dw[1]; p0.u[2]=dw[2]; p0.u[3]=dw[3];
            p1.u[0]=dw[4]; p1.u[1]=dw[5]; p1.u[2]=dw[6]; p1.u[3]=dw[7];
            acc1 = __builtin_amdgcn_mfma_f32_32x32x16_bf16(a2t0, p0.v, acc1, 0, 0, 0);
            acc1 = __builtin_amdgcn_mfma_f32_32x32x16_bf16(a2t1, p1.v, acc1, 0, 0, 0);
        }
    }

    // Cross-wave reduce. acc regs 0..7 hold m=(r&3)+8*(r>>2)+4h for col n=nl.
    __shared__ float red[2][8][64][8];   // 32 KiB
    #pragma unroll
    for (int r = 0; r < 8; ++r) { red[0][w][l][r] = acc0[r]; red[1][w][l][r] = acc1[r]; }
    __syncthreads();

    const int n_l = tid >> 4;
    const int m   = tid & 15;
    const int li  = n_l + 32 * ((m >> 2) & 1);
    const int r   = (m & 3) + 4 * (m >> 3);
    #pragma unroll
    for (int t = 0; t < 2; ++t) {
        float ssum = 0.f;
        #pragma unroll
        for (int ww = 0; ww < 8; ++ww) ssum += red[t][ww][li][r];
        out[(size_t)(rowbase + 32 * t + n_l) * MDIM + m] = ssum;
    }
}

// ---------------- fallback (round-1 kernel, known-correct) ----------------
constexpr int FB_WAVES = 8, FB_BLOCK = 512, FB_ROWS = 64, FB_FPW = NFEAT / FB_WAVES;
__global__ __launch_bounds__(FB_BLOCK) void km_fused(
    const float* __restrict__ x, const float* __restrict__ a,
    const float* __restrict__ b, const float* __restrict__ W,
    float* __restrict__ out)
{
    const int lane = threadIdx.x & 63, wave = threadIdx.x >> 6;
    const int row  = blockIdx.x * FB_ROWS + lane;
    float xr[DIMD];
    const float4* xp = reinterpret_cast<const float4*>(x + (size_t)row * DIMD);
    #pragma unroll
    for (int i = 0; i < 4; ++i) {
        float4 v = xp[i];
        xr[4*i] = v.x; xr[4*i+1] = v.y; xr[4*i+2] = v.z; xr[4*i+3] = v.w;
    }
    float acc[MDIM];
    #pragma unroll
    for (int m = 0; m < MDIM; ++m) acc[m] = 0.f;
    const int fbase = __builtin_amdgcn_readfirstlane(wave * FB_FPW);
    const float* ab = a + (size_t)fbase * DIMD;
    const float* wb = W + (size_t)fbase * MDIM;
    const float* bb = b + fbase;
    #pragma unroll 2
    for (int fi = 0; fi < FB_FPW; ++fi) {
        const float* ar = ab + fi * DIMD;
        const float* wr = wb + fi * MDIM;
        float d0 = 0.f, d1 = 0.f, d2 = 0.f, d3 = 0.f;
        #pragma unroll
        for (int d = 0; d < 4; ++d) {
            d0 = fmaf(xr[d], ar[d], d0);       d1 = fmaf(xr[4+d], ar[4+d], d1);
            d2 = fmaf(xr[8+d], ar[8+d], d2);   d3 = fmaf(xr[12+d], ar[12+d], d3);
        }
        float t = ((d0 + d1) + (d2 + d3)) + bb[fi];
        float cc = __builtin_amdgcn_cosf(t * INV2PI);
        #pragma unroll
        for (int m = 0; m < MDIM; ++m) acc[m] = fmaf(cc, wr[m], acc[m]);
    }
    __shared__ float red[FB_WAVES][FB_ROWS][MDIM];
    #pragma unroll
    for (int m = 0; m < MDIM; m += 4)
        *reinterpret_cast<float4*>(&red[wave][lane][m]) =
            make_float4(acc[m], acc[m+1], acc[m+2], acc[m+3]);
    __syncthreads();
    for (int o = threadIdx.x; o < FB_ROWS * MDIM; o += FB_BLOCK) {
        const int rr = o >> 4, m = o & 15;
        float s = 0.f;
        #pragma unroll
        for (int ww = 0; ww < FB_WAVES; ++ww) s += red[ww][rr][m];
        out[((size_t)blockIdx.x * FB_ROWS + rr) * MDIM + m] = s * SCALE;
    }
}

extern "C" void kernel_launch(void* const* d_in, const int* in_sizes, int n_in,
                              void* d_out, int out_size, void* d_ws, size_t ws_size,
                              hipStream_t stream) {
    const float* x = (const float*)d_in[0];  // [N, D]
    const float* a = (const float*)d_in[1];  // [F, D]
    const float* b = (const float*)d_in[2];  // [F]
    const float* W = (const float*)d_in[3];  // [F*M]
    float* out = (float*)d_out;              // [N, M]

    if (ws_size >= (size_t)WS_NEEDED) {
        unsigned short* ws_a1 = (unsigned short*)((char*)d_ws + WS_A1_OFF);
        unsigned short* ws_a2 = (unsigned short*)((char*)d_ws + WS_A2_OFF);
        float*          ws_bs = (float*)((char*)d_ws + WS_BS_OFF);
        km_prep<<<dim3(128), dim3(64), 0, stream>>>(a, b, W, ws_a1, ws_a2, ws_bs);
        km_mfma<<<dim3(NPTS / 64), dim3(512), 0, stream>>>(x, ws_a1, ws_a2, ws_bs, out);
    } else {
        km_fused<<<dim3(NPTS / FB_ROWS), dim3(FB_BLOCK), 0, stream>>>(x, a, b, W, out);
    }
}